// Round 1
// baseline (648.690 us; speedup 1.0000x reference)
//
#include <hip/hip_runtime.h>
#include <hip/hip_bf16.h>

#define MPB 32            // samples per block
#define NBLK (131072 / MPB)

typedef __attribute__((ext_vector_type(8))) short bf16x8;
typedef __attribute__((ext_vector_type(4))) float f32x4;
typedef __attribute__((ext_vector_type(8))) unsigned short u16x8;

// ---------------- weight prep: fp32 -> bf16 (fc1 zero-padded K 360->384) ----
__global__ __launch_bounds__(256) void prep_weights(
    const float* __restrict__ fc1w, const float* __restrict__ fc2w,
    __hip_bfloat16* __restrict__ w1o, __hip_bfloat16* __restrict__ w2o)
{
    int id = blockIdx.x * 256 + threadIdx.x;
    if (id < 256 * 384) {
        int n = id / 384, k = id - n * 384;
        float v = (k < 360) ? fc1w[n * 360 + k] : 0.0f;
        w1o[id] = __float2bfloat16(v);
    } else {
        int id2 = id - 256 * 384;
        if (id2 < 64 * 256) w2o[id2] = __float2bfloat16(fc2w[id2]);
    }
}

// ---------------- fused pipeline ----------------
// LDS layout (bytes), total 65096 <= 64KiB:
//   Sraw  f32 [32][150] @ 0      (dead after std)
//   SD   bf16 [32][120] @ 19200  (dead after conv1)
//   C1   bf16 [32][192] @ 26880  (dead after conv2)
//   F    bf16 [32][392] @ 39168  (dead after fc1 A-frag load)
//   Bp   bf16 [32][392] @ 0      (fc weight chunks; over dead Sraw+SD)
//   H1   bf16 [32][264] @ 39168  (over dead F)
//   H2   f32  [32][72]  @ 26880  (over dead C1)
//   cw   f32  [210]     @ 64256  (conv weights+biases, loaded once)
__global__ __launch_bounds__(256, 2) void fused_convnet(
    const float* __restrict__ sig,
    const float* __restrict__ c1w_g, const float* __restrict__ c1b_g,
    const float* __restrict__ c2w_g, const float* __restrict__ c2b_g,
    const float* __restrict__ fc1b, const float* __restrict__ fc2b,
    const float* __restrict__ pw, const float* __restrict__ pb,
    const __hip_bfloat16* __restrict__ W1, const __hip_bfloat16* __restrict__ W2,
    float* __restrict__ out)
{
    __shared__ __align__(16) unsigned char smem[65096];
    float*          Sraw = (float*)smem;
    __hip_bfloat16* SD   = (__hip_bfloat16*)(smem + 19200);
    __hip_bfloat16* C1   = (__hip_bfloat16*)(smem + 26880);
    __hip_bfloat16* F    = (__hip_bfloat16*)(smem + 39168);
    __hip_bfloat16* Bp   = (__hip_bfloat16*)(smem);
    __hip_bfloat16* H1   = (__hip_bfloat16*)(smem + 39168);
    float*          H2   = (float*)(smem + 26880);
    float*          cw   = (float*)(smem + 64256);

    const int tid = threadIdx.x;
    const int sBase = blockIdx.x * MPB;

    // ---- phase 0: stage signal tile + conv consts ----
    {
        const float4* gs = (const float4*)(sig + (size_t)sBase * 150);
        float4* ls = (float4*)Sraw;
        #pragma unroll
        for (int it = 0; it < 5; ++it) {           // 1200 float4 = 32*150 floats
            int i = tid + it * 256;
            if (i < 1200) ls[i] = gs[i];
        }
        if (tid < 210) {
            float v;
            if (tid < 45)       v = c1w_g[tid];
            else if (tid < 50)  v = c1b_g[tid - 45];
            else if (tid < 200) v = c2w_g[tid - 50];
            else                v = c2b_g[tid - 200];
            cw[tid] = v;
        }
    }
    __syncthreads();

    // ---- phase 1: running std (window 10, ddof=1) -> SD[s][c*40+t] ----
    for (int id = tid; id < 32 * 120; id += 256) {
        int s = id / 120, r = id - s * 120;
        int c = r / 40, t = r - c * 40;
        const float* p = Sraw + s * 150 + t * 3 + c;
        float sum = 0.f, sq = 0.f;
        #pragma unroll
        for (int j = 0; j < 10; ++j) { float x = p[j * 3]; sum += x; sq += x * x; }
        float var = (sq - sum * sum * 0.1f) * (1.0f / 9.0f);
        SD[id] = __float2bfloat16(sqrtf(fmaxf(var, 0.f)));
    }
    __syncthreads();

    // ---- phase 2: conv1 (5,3,3) + relu -> C1[s][o*38+t] ----
    for (int id = tid; id < 32 * 190; id += 256) {
        int s = id / 190, r = id - s * 190;
        int o = r / 38, t = r - o * 38;
        float acc = cw[45 + o];
        const float* w = cw + o * 9;
        const __hip_bfloat16* x = SD + s * 120 + t;
        #pragma unroll
        for (int i = 0; i < 3; ++i)
            #pragma unroll
            for (int k = 0; k < 3; ++k)
                acc += w[i * 3 + k] * __bfloat162float(x[i * 40 + k]);
        C1[s * 192 + r] = __float2bfloat16(fmaxf(acc, 0.f));
    }
    __syncthreads();

    // ---- phase 3: conv2 (10,5,3) + relu -> F[s][t*10+o]; zero-pad K tail ----
    for (int id = tid; id < 32 * 32; id += 256) {
        int s = id >> 5, j = id & 31;
        F[s * 392 + 360 + j] = __float2bfloat16(0.f);
    }
    for (int id = tid; id < 32 * 360; id += 256) {
        int s = id / 360, r = id - s * 360;
        int o = r / 36, t = r - o * 36;
        float acc = cw[200 + o];
        const float* w = cw + 50 + o * 15;
        const __hip_bfloat16* x = C1 + s * 192 + t;
        #pragma unroll
        for (int i = 0; i < 5; ++i)
            #pragma unroll
            for (int k = 0; k < 3; ++k)
                acc += w[i * 3 + k] * __bfloat162float(x[i * 38 + k]);
        F[s * 392 + t * 10 + o] = __float2bfloat16(fmaxf(acc, 0.f));
    }
    __syncthreads();

    // ---- FC phases: per-wave 16x16 MFMA tiles ----
    const int wv   = tid >> 6;
    const int lane = tid & 63;
    const int mrow = lane & 15;     // A-row / B-col / D-col
    const int kgrp = lane >> 4;     // k-group 0..3
    const int m0 = (wv & 1) * 16;   // M-tile
    const int nt = (wv >> 1);       // N-tile within 32-wide chunk

    // fc1 A-fragments (K=384 -> 12 frags), held in regs for all chunks
    bf16x8 a1[12];
    #pragma unroll
    for (int kk = 0; kk < 12; ++kk)
        a1[kk] = *(const bf16x8*)&F[(m0 + mrow) * 392 + kk * 32 + kgrp * 8];

    // fc1: 8 chunks of N=32
    for (int c = 0; c < 8; ++c) {
        __syncthreads();                       // prev chunk compute / A-frag loads done
        {
            const u16x8* src = (const u16x8*)(W1 + c * 32 * 384);
            #pragma unroll
            for (int it = 0; it < 6; ++it) {   // 1536 vec16 = 32 rows * 48
                int v = tid + it * 256;
                int n = v / 48, k8 = v - n * 48;
                *(u16x8*)((unsigned short*)Bp + n * 392 + k8 * 8) = src[v];
            }
        }
        __syncthreads();
        f32x4 acc = {0.f, 0.f, 0.f, 0.f};
        #pragma unroll
        for (int kk = 0; kk < 12; ++kk) {
            bf16x8 b = *(const bf16x8*)&Bp[(nt * 16 + mrow) * 392 + kk * 32 + kgrp * 8];
            acc = __builtin_amdgcn_mfma_f32_16x16x32_bf16(a1[kk], b, acc, 0, 0, 0);
        }
        int n = c * 32 + nt * 16 + mrow;
        float bias = fc1b[n];
        #pragma unroll
        for (int i = 0; i < 4; ++i) {
            int row = m0 + kgrp * 4 + i;
            float h = fmaxf(acc[i] + bias, 0.f);
            H1[row * 264 + n] = __float2bfloat16(h);
        }
    }
    __syncthreads();

    // fc2 A-fragments (K=256 -> 8 frags)
    bf16x8 a2[8];
    #pragma unroll
    for (int kk = 0; kk < 8; ++kk)
        a2[kk] = *(const bf16x8*)&H1[(m0 + mrow) * 264 + kk * 32 + kgrp * 8];

    // fc2: 2 chunks of N=32
    for (int c = 0; c < 2; ++c) {
        __syncthreads();
        {
            const u16x8* src = (const u16x8*)(W2 + c * 32 * 256);
            #pragma unroll
            for (int it = 0; it < 4; ++it) {   // 1024 vec16 = 32 rows * 32
                int v = tid + it * 256;
                int n = v >> 5, k8 = v & 31;
                *(u16x8*)((unsigned short*)Bp + n * 264 + k8 * 8) = src[v];
            }
        }
        __syncthreads();
        f32x4 acc = {0.f, 0.f, 0.f, 0.f};
        #pragma unroll
        for (int kk = 0; kk < 8; ++kk) {
            bf16x8 b = *(const bf16x8*)&Bp[(nt * 16 + mrow) * 264 + kk * 32 + kgrp * 8];
            acc = __builtin_amdgcn_mfma_f32_16x16x32_bf16(a2[kk], b, acc, 0, 0, 0);
        }
        int n = c * 32 + nt * 16 + mrow;
        float bias = fc2b[n];
        #pragma unroll
        for (int i = 0; i < 4; ++i) {
            int row = m0 + kgrp * 4 + i;
            float h = fmaxf(acc[i] + bias, 0.f);
            H2[row * 72 + n] = h;
        }
    }
    __syncthreads();

    // ---- pamap head (64->12) + log_softmax; 4 threads per sample ----
    if (tid < 128) {
        int s = tid >> 2, q = tid & 3;
        const float* h = H2 + s * 72;
        float lg[3];
        #pragma unroll
        for (int jj = 0; jj < 3; ++jj) {
            int j = q * 3 + jj;
            float acc = pb[j];
            const float* w = pw + j * 64;
            #pragma unroll
            for (int k = 0; k < 64; ++k) acc += w[k] * h[k];
            lg[jj] = acc;
        }
        float m = fmaxf(lg[0], fmaxf(lg[1], lg[2]));
        m = fmaxf(m, __shfl_xor(m, 1, 4));
        m = fmaxf(m, __shfl_xor(m, 2, 4));
        float e = expf(lg[0] - m) + expf(lg[1] - m) + expf(lg[2] - m);
        e += __shfl_xor(e, 1, 4);
        e += __shfl_xor(e, 2, 4);
        float lse = m + logf(e);
        float* op = out + (size_t)(sBase + s) * 12 + q * 3;
        op[0] = lg[0] - lse;
        op[1] = lg[1] - lse;
        op[2] = lg[2] - lse;
    }
}

extern "C" void kernel_launch(void* const* d_in, const int* in_sizes, int n_in,
                              void* d_out, int out_size, void* d_ws, size_t ws_size,
                              hipStream_t stream) {
    const float* sig = (const float*)d_in[0];
    const float* c1w = (const float*)d_in[1];
    const float* c1b = (const float*)d_in[2];
    const float* c2w = (const float*)d_in[3];
    const float* c2b = (const float*)d_in[4];
    const float* f1w = (const float*)d_in[5];
    const float* f1b = (const float*)d_in[6];
    const float* f2w = (const float*)d_in[7];
    const float* f2b = (const float*)d_in[8];
    const float* pw  = (const float*)d_in[9];
    const float* pb  = (const float*)d_in[10];
    float* out = (float*)d_out;

    __hip_bfloat16* W1 = (__hip_bfloat16*)d_ws;                       // [256][384]
    __hip_bfloat16* W2 = (__hip_bfloat16*)((char*)d_ws + 196608);     // [64][256]

    prep_weights<<<448, 256, 0, stream>>>(f1w, f2w, W1, W2);
    fused_convnet<<<NBLK, 256, 0, stream>>>(sig, c1w, c1b, c2w, c2b,
                                            f1b, f2b, pw, pb, W1, W2, out);
}

// Round 2
// 254.252 us; speedup vs baseline: 2.5514x; 2.5514x over previous
//
#include <hip/hip_runtime.h>
#include <hip/hip_bf16.h>

typedef __attribute__((ext_vector_type(8))) short bf16x8;
typedef __attribute__((ext_vector_type(4))) short short4v;
typedef __attribute__((ext_vector_type(4))) float f32x4;
typedef __attribute__((ext_vector_type(8))) unsigned short u16x8;

// ---------------- weight prep: fp32 -> bf16 (fc1 zero-padded K 360->384) ----
__global__ __launch_bounds__(256) void prep_weights(
    const float* __restrict__ fc1w, const float* __restrict__ fc2w,
    __hip_bfloat16* __restrict__ w1o, __hip_bfloat16* __restrict__ w2o)
{
    int id = blockIdx.x * 256 + threadIdx.x;
    if (id < 256 * 384) {
        int n = id / 384, k = id - n * 384;
        float v = (k < 360) ? fc1w[n * 360 + k] : 0.0f;
        w1o[id] = __float2bfloat16(v);
    } else {
        int id2 = id - 256 * 384;
        if (id2 < 64 * 256) w2o[id2] = __float2bfloat16(fc2w[id2]);
    }
}

// =================== K1: features (std + conv1 + conv2) ====================
// 16 samples/block, 256 threads, LDS 31176 B -> 5 blocks/CU.
// LDS overlays: Sraw f32[16][150] @0 (dead after std)
//               SD   f32[16][124] @9600  (c*40+t; dead after conv1)
//               C1   f32[16][200] @17536 (o*40+t; dead after conv2)
//               Fl  bf16[16][384] @0     (over dead Sraw + dead SD head)
//               cw   f32[210]     @30336
__global__ __launch_bounds__(256, 4) void features_kernel(
    const float* __restrict__ sig,
    const float* __restrict__ c1w_g, const float* __restrict__ c1b_g,
    const float* __restrict__ c2w_g, const float* __restrict__ c2b_g,
    __hip_bfloat16* __restrict__ Fg)
{
    __shared__ __align__(16) unsigned char smem[31176];
    float* Sraw = (float*)smem;
    float* SD   = (float*)(smem + 9600);
    float* C1   = (float*)(smem + 17536);
    __hip_bfloat16* Fl = (__hip_bfloat16*)smem;
    float* cw   = (float*)(smem + 30336);

    const int tid = threadIdx.x;
    const int blk = blockIdx.x;

    // phase 0: stage 16x150 f32 (600 float4) + conv consts
    {
        const float4* gs = (const float4*)(sig + (size_t)blk * 2400);
        float4* ls = (float4*)Sraw;
        #pragma unroll
        for (int it = 0; it < 3; ++it) {
            int i = tid + it * 256;
            if (i < 600) ls[i] = gs[i];
        }
        if (tid < 210) {
            float v;
            if (tid < 45)       v = c1w_g[tid];
            else if (tid < 50)  v = c1b_g[tid - 45];
            else if (tid < 200) v = c2w_g[tid - 50];
            else                v = c2b_g[tid - 200];
            cw[tid] = v;
        }
    }
    __syncthreads();

    // phase 1: running std, sliding window. 192 tasks: (s, c, quarter of 10 windows)
    if (tid < 192) {
        int s = tid / 12, r = tid - s * 12;
        int c = r >> 2, q = r & 3;
        const float* p = Sraw + s * 150 + c + q * 30;   // values j*3
        float x[19];
        #pragma unroll
        for (int j = 0; j < 19; ++j) x[j] = p[j * 3];
        float sum = 0.f, sq = 0.f;
        #pragma unroll
        for (int j = 0; j < 10; ++j) { sum += x[j]; sq += x[j] * x[j]; }
        float* o = SD + s * 124 + c * 40 + q * 10;
        #pragma unroll
        for (int i = 0; i < 10; ++i) {
            float var = (sq - sum * sum * 0.1f) * (1.0f / 9.0f);
            o[i] = sqrtf(fmaxf(var, 0.f));
            if (i < 9) {
                float d = x[i + 10] - x[i];
                sq  += d * (x[i + 10] + x[i]);
                sum += d;
            }
        }
    }
    __syncthreads();

    // phase 2: conv1 (5,3,3)+relu. tasks (s,t): 608; 9 shared loads -> 5 outputs
    for (int id = tid; id < 608; id += 256) {
        int s = id / 38, t = id - s * 38;
        float xs[9];
        #pragma unroll
        for (int c = 0; c < 3; ++c)
            #pragma unroll
            for (int k = 0; k < 3; ++k)
                xs[c * 3 + k] = SD[s * 124 + c * 40 + t + k];
        #pragma unroll
        for (int o = 0; o < 5; ++o) {
            float acc = cw[45 + o];
            #pragma unroll
            for (int j = 0; j < 9; ++j) acc += cw[o * 9 + j] * xs[j];
            C1[s * 200 + o * 40 + t] = fmaxf(acc, 0.f);
        }
    }
    __syncthreads();

    // phase 3: conv2 (10,5,3)+relu -> Fl bf16 [s][t*10+o]; zero K-tail
    if (tid < 192) {     // 16 samples x 12 u32 of zero tail [360,384)
        int s = tid / 12, j = tid - s * 12;
        *(unsigned int*)((unsigned char*)smem + s * 768 + 720 + 4 * j) = 0u;
    }
    for (int id = tid; id < 576; id += 256) {
        int s = id / 36, t = id - s * 36;
        float xs[15];
        #pragma unroll
        for (int i = 0; i < 5; ++i)
            #pragma unroll
            for (int k = 0; k < 3; ++k)
                xs[i * 3 + k] = C1[s * 200 + i * 40 + t + k];
        #pragma unroll
        for (int o = 0; o < 10; ++o) {
            float acc = cw[200 + o];
            #pragma unroll
            for (int j = 0; j < 15; ++j) acc += cw[50 + o * 15 + j] * xs[j];
            Fl[s * 384 + t * 10 + o] = __float2bfloat16(fmaxf(acc, 0.f));
        }
    }
    __syncthreads();

    // phase 4: coalesced copy-out, 768 u16x8
    {
        const u16x8* src = (const u16x8*)smem;
        u16x8* dst = (u16x8*)Fg + (size_t)blk * 768;
        #pragma unroll
        for (int it = 0; it < 3; ++it) dst[tid + it * 256] = src[tid + it * 256];
    }
}

// =================== K2: fc1 + fc2 + pamap head + log_softmax ==============
// 64 samples/block (wave w owns 16), 2048 blocks. Weights = A operand
// (D-row = weight row, D-col = sample); activations stay in registers.
// LDS: Wb bf16[32][392] @0 (25088) | Tb 4x1KB wave transpose @25088
//      pwl f32[768] @29184 | pbl f32[12] @32256   -> 32304 B total
__global__ __launch_bounds__(256, 3) void fc_head_kernel(
    const __hip_bfloat16* __restrict__ Fg,
    const __hip_bfloat16* __restrict__ W1, const __hip_bfloat16* __restrict__ W2,
    const float* __restrict__ fc1b, const float* __restrict__ fc2b,
    const float* __restrict__ pw, const float* __restrict__ pb,
    float* __restrict__ out)
{
    __shared__ __align__(16) unsigned char smem[32304];
    __hip_bfloat16* Wb = (__hip_bfloat16*)smem;
    float* pwl = (float*)(smem + 29184);
    float* pbl = (float*)(smem + 32256);

    const int tid  = threadIdx.x;
    const int blk  = blockIdx.x;
    const int w    = tid >> 6;
    const int lane = tid & 63;
    const int ml   = lane & 15;       // sample-in-tile / weight-row-in-tile
    const int kg   = lane >> 4;       // k-group
    unsigned char* Tw = smem + 25088 + w * 1024;   // wave-private [16][32] bf16

    // head weights -> LDS
    for (int i = tid; i < 780; i += 256) {
        if (i < 768) pwl[i] = pw[i]; else pbl[i - 768] = pb[i - 768];
    }

    // activation B-fragments: 12 x bf16x8, kept in regs for the whole kernel
    const __hip_bfloat16* myF = Fg + (size_t)(blk * 64 + w * 16 + ml) * 384;
    bf16x8 bfr[12];
    #pragma unroll
    for (int kk = 0; kk < 12; ++kk)
        bfr[kk] = *(const bf16x8*)(myF + kk * 32 + kg * 8);

    // stage W1 chunk 0
    {
        const u16x8* src = (const u16x8*)W1;
        #pragma unroll
        for (int it = 0; it < 6; ++it) {
            int v = tid + it * 256;
            int n = v / 48, k8 = v - n * 48;
            *(u16x8*)(Wb + n * 392 + k8 * 8) = src[v];
        }
    }
    __syncthreads();

    f32x4 acc2[4] = {f32x4{0,0,0,0}, f32x4{0,0,0,0}, f32x4{0,0,0,0}, f32x4{0,0,0,0}};

    for (int c = 0; c < 8; ++c) {
        // T14: issue next chunk's global loads early (consumed after barrier)
        u16x8 nf[6];
        if (c < 7) {
            const u16x8* src = (const u16x8*)(W1 + (c + 1) * 32 * 384);
            #pragma unroll
            for (int it = 0; it < 6; ++it) nf[it] = src[tid + it * 256];
        }

        // fc1: two 16-row weight tiles vs this wave's 16 samples
        f32x4 accA = {0,0,0,0}, accB = {0,0,0,0};
        #pragma unroll
        for (int kk = 0; kk < 12; ++kk) {
            bf16x8 a0 = *(const bf16x8*)(Wb + ml * 392 + kk * 32 + kg * 8);
            bf16x8 a1 = *(const bf16x8*)(Wb + (16 + ml) * 392 + kk * 32 + kg * 8);
            accA = __builtin_amdgcn_mfma_f32_16x16x32_bf16(a0, bfr[kk], accA, 0, 0, 0);
            accB = __builtin_amdgcn_mfma_f32_16x16x32_bf16(a1, bfr[kk], accB, 0, 0, 0);
        }
        // bias + relu + bf16, write wave-private transpose slot
        {
            float4 b4 = *(const float4*)(fc1b + c * 32 + kg * 4);
            short4v hv;
            #pragma unroll
            for (int i = 0; i < 4; ++i) {
                __hip_bfloat16 h = __float2bfloat16(fmaxf(accA[i] + ((const float*)&b4)[i], 0.f));
                hv[i] = *(short*)&h;
            }
            *(short4v*)(Tw + ml * 64 + kg * 8) = hv;
        }
        {
            float4 b4 = *(const float4*)(fc1b + c * 32 + 16 + kg * 4);
            short4v hv;
            #pragma unroll
            for (int i = 0; i < 4; ++i) {
                __hip_bfloat16 h = __float2bfloat16(fmaxf(accB[i] + ((const float*)&b4)[i], 0.f));
                hv[i] = *(short*)&h;
            }
            *(short4v*)(Tw + ml * 64 + 32 + kg * 8) = hv;
        }
        asm volatile("s_waitcnt lgkmcnt(0)" ::: "memory");
        __builtin_amdgcn_sched_barrier(0);

        // fc2 partial: B-frag from transpose slot, A-frags (W2) direct from L2
        bf16x8 pf = *(const bf16x8*)(Tw + ml * 64 + kg * 16);
        #pragma unroll
        for (int t2 = 0; t2 < 4; ++t2) {
            bf16x8 a2 = *(const bf16x8*)(W2 + (t2 * 16 + ml) * 256 + c * 32 + kg * 8);
            acc2[t2] = __builtin_amdgcn_mfma_f32_16x16x32_bf16(a2, pf, acc2[t2], 0, 0, 0);
        }

        __syncthreads();
        if (c < 7) {
            #pragma unroll
            for (int it = 0; it < 6; ++it) {
                int v = tid + it * 256;
                int n = v / 48, k8 = v - n * 48;
                *(u16x8*)(Wb + n * 392 + k8 * 8) = nf[it];
            }
        }
        __syncthreads();
    }

    // ---- head: h = relu(fc2+bias); logits = pw@h + pb; log_softmax ----
    float h[16];
    #pragma unroll
    for (int t2 = 0; t2 < 4; ++t2) {
        float4 b4 = *(const float4*)(fc2b + t2 * 16 + kg * 4);
        #pragma unroll
        for (int i = 0; i < 4; ++i)
            h[t2 * 4 + i] = fmaxf(acc2[t2][i] + ((const float*)&b4)[i], 0.f);
    }
    float lg[12];
    #pragma unroll
    for (int j = 0; j < 12; ++j) {
        float s = 0.f;
        #pragma unroll
        for (int t2 = 0; t2 < 4; ++t2) {
            float4 wv = *(const float4*)(pwl + j * 64 + t2 * 16 + kg * 4);
            s += wv.x * h[t2 * 4 + 0] + wv.y * h[t2 * 4 + 1]
               + wv.z * h[t2 * 4 + 2] + wv.w * h[t2 * 4 + 3];
        }
        lg[j] = s;
    }
    #pragma unroll
    for (int j = 0; j < 12; ++j) {
        lg[j] += __shfl_xor(lg[j], 16);
        lg[j] += __shfl_xor(lg[j], 32);
        lg[j] += pbl[j];
    }
    float m = lg[0];
    #pragma unroll
    for (int j = 1; j < 12; ++j) m = fmaxf(m, lg[j]);
    float e = 0.f;
    #pragma unroll
    for (int j = 0; j < 12; ++j) e += __expf(lg[j] - m);
    float lse = m + __logf(e);
    if (kg == 0) {
        float* op = out + (size_t)(blk * 64 + w * 16 + ml) * 12;
        float4 o0 = {lg[0] - lse, lg[1] - lse, lg[2]  - lse, lg[3]  - lse};
        float4 o1 = {lg[4] - lse, lg[5] - lse, lg[6]  - lse, lg[7]  - lse};
        float4 o2 = {lg[8] - lse, lg[9] - lse, lg[10] - lse, lg[11] - lse};
        ((float4*)op)[0] = o0; ((float4*)op)[1] = o1; ((float4*)op)[2] = o2;
    }
}

// =================== fallback: round-1 fused kernel (ws too small) =========
__global__ __launch_bounds__(256, 2) void fused_convnet(
    const float* __restrict__ sig,
    const float* __restrict__ c1w_g, const float* __restrict__ c1b_g,
    const float* __restrict__ c2w_g, const float* __restrict__ c2b_g,
    const float* __restrict__ fc1b, const float* __restrict__ fc2b,
    const float* __restrict__ pw, const float* __restrict__ pb,
    const __hip_bfloat16* __restrict__ W1, const __hip_bfloat16* __restrict__ W2,
    float* __restrict__ out)
{
    __shared__ __align__(16) unsigned char smem[65096];
    float*          Sraw = (float*)smem;
    __hip_bfloat16* SD   = (__hip_bfloat16*)(smem + 19200);
    __hip_bfloat16* C1   = (__hip_bfloat16*)(smem + 26880);
    __hip_bfloat16* F    = (__hip_bfloat16*)(smem + 39168);
    __hip_bfloat16* Bp   = (__hip_bfloat16*)(smem);
    __hip_bfloat16* H1   = (__hip_bfloat16*)(smem + 39168);
    float*          H2   = (float*)(smem + 26880);
    float*          cw   = (float*)(smem + 64256);

    const int tid = threadIdx.x;
    const int sBase = blockIdx.x * 32;

    {
        const float4* gs = (const float4*)(sig + (size_t)sBase * 150);
        float4* ls = (float4*)Sraw;
        #pragma unroll
        for (int it = 0; it < 5; ++it) {
            int i = tid + it * 256;
            if (i < 1200) ls[i] = gs[i];
        }
        if (tid < 210) {
            float v;
            if (tid < 45)       v = c1w_g[tid];
            else if (tid < 50)  v = c1b_g[tid - 45];
            else if (tid < 200) v = c2w_g[tid - 50];
            else                v = c2b_g[tid - 200];
            cw[tid] = v;
        }
    }
    __syncthreads();
    for (int id = tid; id < 32 * 120; id += 256) {
        int s = id / 120, r = id - s * 120;
        int c = r / 40, t = r - c * 40;
        const float* p = Sraw + s * 150 + t * 3 + c;
        float sum = 0.f, sq = 0.f;
        #pragma unroll
        for (int j = 0; j < 10; ++j) { float x = p[j * 3]; sum += x; sq += x * x; }
        float var = (sq - sum * sum * 0.1f) * (1.0f / 9.0f);
        SD[id] = __float2bfloat16(sqrtf(fmaxf(var, 0.f)));
    }
    __syncthreads();
    for (int id = tid; id < 32 * 190; id += 256) {
        int s = id / 190, r = id - s * 190;
        int o = r / 38, t = r - o * 38;
        float acc = cw[45 + o];
        const float* w = cw + o * 9;
        const __hip_bfloat16* x = SD + s * 120 + t;
        #pragma unroll
        for (int i = 0; i < 3; ++i)
            #pragma unroll
            for (int k = 0; k < 3; ++k)
                acc += w[i * 3 + k] * __bfloat162float(x[i * 40 + k]);
        C1[s * 192 + r] = __float2bfloat16(fmaxf(acc, 0.f));
    }
    __syncthreads();
    for (int id = tid; id < 32 * 32; id += 256) {
        int s = id >> 5, j = id & 31;
        F[s * 392 + 360 + j] = __float2bfloat16(0.f);
    }
    for (int id = tid; id < 32 * 360; id += 256) {
        int s = id / 360, r = id - s * 360;
        int o = r / 36, t = r - o * 36;
        float acc = cw[200 + o];
        const float* w = cw + 50 + o * 15;
        const __hip_bfloat16* x = C1 + s * 192 + t;
        #pragma unroll
        for (int i = 0; i < 5; ++i)
            #pragma unroll
            for (int k = 0; k < 3; ++k)
                acc += w[i * 3 + k] * __bfloat162float(x[i * 38 + k]);
        F[s * 392 + t * 10 + o] = __float2bfloat16(fmaxf(acc, 0.f));
    }
    __syncthreads();

    const int wv   = tid >> 6;
    const int lane = tid & 63;
    const int mrow = lane & 15;
    const int kgrp = lane >> 4;
    const int m0 = (wv & 1) * 16;
    const int nt = (wv >> 1);

    bf16x8 a1[12];
    #pragma unroll
    for (int kk = 0; kk < 12; ++kk)
        a1[kk] = *(const bf16x8*)&F[(m0 + mrow) * 392 + kk * 32 + kgrp * 8];

    for (int c = 0; c < 8; ++c) {
        __syncthreads();
        {
            const u16x8* src = (const u16x8*)(W1 + c * 32 * 384);
            #pragma unroll
            for (int it = 0; it < 6; ++it) {
                int v = tid + it * 256;
                int n = v / 48, k8 = v - n * 48;
                *(u16x8*)((unsigned short*)Bp + n * 392 + k8 * 8) = src[v];
            }
        }
        __syncthreads();
        f32x4 acc = {0.f, 0.f, 0.f, 0.f};
        #pragma unroll
        for (int kk = 0; kk < 12; ++kk) {
            bf16x8 b = *(const bf16x8*)&Bp[(nt * 16 + mrow) * 392 + kk * 32 + kgrp * 8];
            acc = __builtin_amdgcn_mfma_f32_16x16x32_bf16(a1[kk], b, acc, 0, 0, 0);
        }
        int n = c * 32 + nt * 16 + mrow;
        float bias = fc1b[n];
        #pragma unroll
        for (int i = 0; i < 4; ++i) {
            int row = m0 + kgrp * 4 + i;
            float h = fmaxf(acc[i] + bias, 0.f);
            H1[row * 264 + n] = __float2bfloat16(h);
        }
    }
    __syncthreads();

    bf16x8 a2[8];
    #pragma unroll
    for (int kk = 0; kk < 8; ++kk)
        a2[kk] = *(const bf16x8*)&H1[(m0 + mrow) * 264 + kk * 32 + kgrp * 8];

    for (int c = 0; c < 2; ++c) {
        __syncthreads();
        {
            const u16x8* src = (const u16x8*)(W2 + c * 32 * 256);
            #pragma unroll
            for (int it = 0; it < 4; ++it) {
                int v = tid + it * 256;
                int n = v >> 5, k8 = v & 31;
                *(u16x8*)((unsigned short*)Bp + n * 264 + k8 * 8) = src[v];
            }
        }
        __syncthreads();
        f32x4 acc = {0.f, 0.f, 0.f, 0.f};
        #pragma unroll
        for (int kk = 0; kk < 8; ++kk) {
            bf16x8 b = *(const bf16x8*)&Bp[(nt * 16 + mrow) * 264 + kk * 32 + kgrp * 8];
            acc = __builtin_amdgcn_mfma_f32_16x16x32_bf16(a2[kk], b, acc, 0, 0, 0);
        }
        int n = c * 32 + nt * 16 + mrow;
        float bias = fc2b[n];
        #pragma unroll
        for (int i = 0; i < 4; ++i) {
            int row = m0 + kgrp * 4 + i;
            float h = fmaxf(acc[i] + bias, 0.f);
            H2[row * 72 + n] = h;
        }
    }
    __syncthreads();

    if (tid < 128) {
        int s = tid >> 2, q = tid & 3;
        const float* h = H2 + s * 72;
        float lg[3];
        #pragma unroll
        for (int jj = 0; jj < 3; ++jj) {
            int j = q * 3 + jj;
            float acc = pb[j];
            const float* w = pw + j * 64;
            #pragma unroll
            for (int k = 0; k < 64; ++k) acc += w[k] * h[k];
            lg[jj] = acc;
        }
        float m = fmaxf(lg[0], fmaxf(lg[1], lg[2]));
        m = fmaxf(m, __shfl_xor(m, 1, 4));
        m = fmaxf(m, __shfl_xor(m, 2, 4));
        float e = expf(lg[0] - m) + expf(lg[1] - m) + expf(lg[2] - m);
        e += __shfl_xor(e, 1, 4);
        e += __shfl_xor(e, 2, 4);
        float lse = m + logf(e);
        float* op = out + (size_t)(sBase + s) * 12 + q * 3;
        op[0] = lg[0] - lse;
        op[1] = lg[1] - lse;
        op[2] = lg[2] - lse;
    }
}

extern "C" void kernel_launch(void* const* d_in, const int* in_sizes, int n_in,
                              void* d_out, int out_size, void* d_ws, size_t ws_size,
                              hipStream_t stream) {
    const float* sig = (const float*)d_in[0];
    const float* c1w = (const float*)d_in[1];
    const float* c1b = (const float*)d_in[2];
    const float* c2w = (const float*)d_in[3];
    const float* c2b = (const float*)d_in[4];
    const float* f1w = (const float*)d_in[5];
    const float* f1b = (const float*)d_in[6];
    const float* f2w = (const float*)d_in[7];
    const float* f2b = (const float*)d_in[8];
    const float* pw  = (const float*)d_in[9];
    const float* pb  = (const float*)d_in[10];
    float* out = (float*)d_out;

    __hip_bfloat16* W1 = (__hip_bfloat16*)d_ws;                    // [256][384]
    __hip_bfloat16* W2 = (__hip_bfloat16*)((char*)d_ws + 196608);  // [64][256]
    __hip_bfloat16* Fg = (__hip_bfloat16*)((char*)d_ws + 229376);  // [131072][384]

    prep_weights<<<448, 256, 0, stream>>>(f1w, f2w, W1, W2);

    if (ws_size >= (size_t)229376 + (size_t)131072 * 384 * 2) {
        features_kernel<<<8192, 256, 0, stream>>>(sig, c1w, c1b, c2w, c2b, Fg);
        fc_head_kernel<<<2048, 256, 0, stream>>>(Fg, W1, W2, f1b, f2b, pw, pb, out);
    } else {
        fused_convnet<<<4096, 256, 0, stream>>>(sig, c1w, c1b, c2w, c2b,
                                                f1b, f2b, pw, pb, W1, W2, out);
    }
}

// Round 4
// 245.249 us; speedup vs baseline: 2.6450x; 1.0367x over previous
//
#include <hip/hip_runtime.h>
#include <hip/hip_bf16.h>

typedef __attribute__((ext_vector_type(8))) short bf16x8;
typedef __attribute__((ext_vector_type(4))) float f32x4;
typedef __attribute__((ext_vector_type(8))) unsigned short u16x8;

static __device__ __forceinline__ unsigned short bf16bits(float v) {
    __hip_bfloat16 h = __float2bfloat16(v);
    return *(unsigned short*)&h;
}

// ---- weight prep: fc1 K-permuted (k' = o*36+t) + zero-pad 360->384; fc2 ----
__global__ __launch_bounds__(256) void prep_weights(
    const float* __restrict__ fc1w, const float* __restrict__ fc2w,
    __hip_bfloat16* __restrict__ w1o, __hip_bfloat16* __restrict__ w2o)
{
    int id = blockIdx.x * 256 + threadIdx.x;
    if (id < 256 * 384) {
        int n = id / 384, k2 = id - n * 384;      // k2 = o*36 + t
        float v = 0.0f;
        if (k2 < 360) {
            int o = k2 / 36, t = k2 - o * 36;
            v = fc1w[n * 360 + t * 10 + o];
        }
        w1o[id] = __float2bfloat16(v);
    } else {
        int id2 = id - 256 * 384;
        if (id2 < 64 * 256) w2o[id2] = __float2bfloat16(fc2w[id2]);
    }
}

// =================== K1: features (std + conv1 + conv2) ====================
// 8 samples/block, 256 threads, LDS 16648 B -> 8 blocks/CU (32 waves, 100%).
// LDS: Sraw f32[8][150] packed @0 (4800)   [dead after std]
//      SD   f32[8][3][48]      @4800 (4608)[dead after conv1]
//      C1   f32[8][5][40]      @9408 (6400)[dead after copy]
//      Fl  bf16[8][384]        @0    (6144)[over dead Sraw/SD head]
//      cw   f32[210]           @15808
__global__ __launch_bounds__(256, 8) void features_kernel(
    const float* __restrict__ sig,
    const float* __restrict__ c1w_g, const float* __restrict__ c1b_g,
    const float* __restrict__ c2w_g, const float* __restrict__ c2b_g,
    __hip_bfloat16* __restrict__ Fg)
{
    __shared__ __align__(16) unsigned char smem[16648];
    float* Sraw = (float*)smem;
    float* SD   = (float*)(smem + 4800);
    float* C1   = (float*)(smem + 9408);
    float* cw   = (float*)(smem + 15808);

    const int tid = threadIdx.x;
    const int blk = blockIdx.x;

    // phase 0: stage 8x150 f32 (300 float4) + conv consts
    {
        const float4* gs = (const float4*)(sig + (size_t)blk * 1200);
        float4* ls = (float4*)Sraw;
        for (int i = tid; i < 300; i += 256) ls[i] = gs[i];
        if (tid < 210) {
            float v;
            if (tid < 45)       v = c1w_g[tid];
            else if (tid < 50)  v = c1b_g[tid - 45];
            else if (tid < 200) v = c2w_g[tid - 50];
            else                v = c2b_g[tid - 200];
            cw[tid] = v;
        }
    }
    __syncthreads();

    // phase 1: running std, sliding. 192 tasks: (s, c, q of 5 windows)
    if (tid < 192) {
        int s = tid / 24, r = tid - s * 24;
        int c = r >> 3, q = r & 7;
        const float* p = Sraw + s * 150 + c + q * 15;   // raw t = q*5 + j, ch c
        float x[14];
        #pragma unroll
        for (int j = 0; j < 14; ++j) x[j] = p[j * 3];
        float sum = 0.f, sq = 0.f;
        #pragma unroll
        for (int j = 0; j < 10; ++j) { sum += x[j]; sq += x[j] * x[j]; }
        float* o = SD + (s * 3 + c) * 48 + q * 5;
        #pragma unroll
        for (int i = 0; i < 5; ++i) {
            float var = (sq - sum * sum * 0.1f) * (1.0f / 9.0f);
            o[i] = sqrtf(fmaxf(var, 0.f));
            if (i < 4) {
                float d = x[i + 10] - x[i];
                sq  += d * (x[i + 10] + x[i]);
                sum += d;
            }
        }
    }
    __syncthreads();

    // phase 2: conv1 (5,3,3)+relu. tasks (s,o,tq): 8*5*10 = 400; 4 t's each
    for (int id = tid; id < 400; id += 256) {
        int s = id / 50, r = id - s * 50;
        int o = r / 10, tq = r - o * 10;
        int t0 = tq * 4;
        float b = cw[45 + o];
        float a0 = b, a1 = b, a2 = b, a3 = b;
        #pragma unroll
        for (int ci = 0; ci < 3; ++ci) {
            const float* row = SD + (s * 3 + ci) * 48 + t0;
            float4 ya = *(const float4*)row;
            float4 yb = *(const float4*)(row + 4);
            float w0 = cw[o * 9 + ci * 3 + 0];
            float w1 = cw[o * 9 + ci * 3 + 1];
            float w2 = cw[o * 9 + ci * 3 + 2];
            a0 += w0 * ya.x + w1 * ya.y + w2 * ya.z;
            a1 += w0 * ya.y + w1 * ya.z + w2 * ya.w;
            a2 += w0 * ya.z + w1 * ya.w + w2 * yb.x;
            a3 += w0 * ya.w + w1 * yb.x + w2 * yb.y;
        }
        float* dst = C1 + (s * 5 + o) * 40 + t0;
        if (tq < 9) {
            float4 v = {fmaxf(a0, 0.f), fmaxf(a1, 0.f), fmaxf(a2, 0.f), fmaxf(a3, 0.f)};
            *(float4*)dst = v;
        } else {                      // t = 36,37 only
            dst[0] = fmaxf(a0, 0.f);
            dst[1] = fmaxf(a1, 0.f);
        }
    }
    __syncthreads();

    // phase 3: conv2 (10,5,3)+relu -> Fl bf16 [s][o*36+t]; zero K-tail
    if (tid < 96) {   // 8 samples x 24 bf16 tail [360,384) = 12 u32 each
        int s = tid / 12, j = tid - s * 12;
        *(unsigned int*)(smem + s * 768 + 720 + 4 * j) = 0u;
    }
    for (int id = tid; id < 720; id += 256) {
        int s = id / 90, r = id - s * 90;
        int o = r / 9, tq = r - o * 9;
        int t0 = tq * 4;
        float b = cw[200 + o];
        float a0 = b, a1 = b, a2 = b, a3 = b;
        #pragma unroll
        for (int i2 = 0; i2 < 5; ++i2) {
            const float* row = C1 + (s * 5 + i2) * 40 + t0;
            float4 ya = *(const float4*)row;
            float4 yb = *(const float4*)(row + 4);
            float w0 = cw[50 + o * 15 + i2 * 3 + 0];
            float w1 = cw[50 + o * 15 + i2 * 3 + 1];
            float w2 = cw[50 + o * 15 + i2 * 3 + 2];
            a0 += w0 * ya.x + w1 * ya.y + w2 * ya.z;
            a1 += w0 * ya.y + w1 * ya.z + w2 * ya.w;
            a2 += w0 * ya.z + w1 * ya.w + w2 * yb.x;
            a3 += w0 * ya.w + w1 * yb.x + w2 * yb.y;
        }
        unsigned int p0 = (unsigned int)bf16bits(fmaxf(a0, 0.f))
                        | ((unsigned int)bf16bits(fmaxf(a1, 0.f)) << 16);
        unsigned int p1 = (unsigned int)bf16bits(fmaxf(a2, 0.f))
                        | ((unsigned int)bf16bits(fmaxf(a3, 0.f)) << 16);
        uint2 pk = {p0, p1};
        *(uint2*)(smem + s * 768 + (o * 36 + t0) * 2) = pk;
    }
    __syncthreads();

    // phase 4: coalesced copy-out, 384 u16x8
    {
        const u16x8* srcv = (const u16x8*)smem;
        u16x8* dstv = (u16x8*)Fg + (size_t)blk * 384;
        for (int i = tid; i < 384; i += 256) dstv[i] = srcv[i];
    }
}

// =================== K2: fc1 + fc2 + pamap head + log_softmax ==============
// 128 samples/block, 1024 blocks, 4 waves; wave = 32 samples x all 256 rows.
// Weights = A operand (D-row = weight row, D-col = sample); activations in
// registers (12x2 bf16x8). W1 double-buffered in LDS: ONE barrier per chunk
// (barrier at top, stage-writes at end of iteration).
// LDS: Wb 2x bf16[32][392] @0 (50176) | Tw 4 x [32 smp][stride 80B] @50176
//      pwl f32[768] @60416 | pbl f32[12] @63488  -> 63536 B
__global__ __launch_bounds__(256, 2) void fc_head_kernel(
    const __hip_bfloat16* __restrict__ Fg,
    const __hip_bfloat16* __restrict__ W1, const __hip_bfloat16* __restrict__ W2,
    const float* __restrict__ fc1b, const float* __restrict__ fc2b,
    const float* __restrict__ pw, const float* __restrict__ pb,
    float* __restrict__ out)
{
    __shared__ __align__(16) unsigned char smem[63536];
    float* pwl = (float*)(smem + 60416);
    float* pbl = (float*)(smem + 63488);

    const int tid  = threadIdx.x;
    const int blk  = blockIdx.x;
    const int w    = tid >> 6;
    const int lane = tid & 63;
    const int ml   = lane & 15;       // weight-row-in-tile / sample-in-tile
    const int kg   = lane >> 4;       // k-group
    unsigned char* Tw = smem + 50176 + w * 2560;   // [32 samples][80B]

    for (int i = tid; i < 780; i += 256) {
        if (i < 768) pwl[i] = pw[i]; else pbl[i - 768] = pb[i - 768];
    }

    // activation B-fragments: 12 k-frags x 2 sample tiles, regs for whole kernel
    const __hip_bfloat16* myF = Fg + (size_t)(blk * 128 + w * 32 + ml) * 384;
    bf16x8 bfr[12][2];
    #pragma unroll
    for (int kk = 0; kk < 12; ++kk) {
        bfr[kk][0] = *(const bf16x8*)(myF + kk * 32 + kg * 8);
        bfr[kk][1] = *(const bf16x8*)(myF + 16 * 384 + kk * 32 + kg * 8);
    }

    // stage W1 chunk 0 into buffer 0
    {
        const u16x8* src = (const u16x8*)W1;
        __hip_bfloat16* b0 = (__hip_bfloat16*)smem;
        #pragma unroll
        for (int it = 0; it < 6; ++it) {
            int v = tid + it * 256;
            int n = v / 48, k8 = v - n * 48;
            *(u16x8*)(b0 + n * 392 + k8 * 8) = src[v];
        }
    }

    f32x4 acc2[4][2];
    #pragma unroll
    for (int t2 = 0; t2 < 4; ++t2) {
        acc2[t2][0] = f32x4{0, 0, 0, 0};
        acc2[t2][1] = f32x4{0, 0, 0, 0};
    }

    for (int c = 0; c < 8; ++c) {
        __syncthreads();   // buf[c&1] staged (by end of prev iter) & prev reads done
        const __hip_bfloat16* cur = (const __hip_bfloat16*)(smem + (c & 1) * 25088);

        // T14: issue next chunk's global loads early
        u16x8 nf[6];
        if (c < 7) {
            const u16x8* src = (const u16x8*)(W1 + (c + 1) * 32 * 384);
            #pragma unroll
            for (int it = 0; it < 6; ++it) nf[it] = src[tid + it * 256];
        }

        // fc1: 2 row-tiles x 2 sample-tiles; each A-read feeds 2 MFMAs
        f32x4 a1acc[2][2];
        #pragma unroll
        for (int rt = 0; rt < 2; ++rt) {
            a1acc[rt][0] = f32x4{0, 0, 0, 0};
            a1acc[rt][1] = f32x4{0, 0, 0, 0};
        }
        #pragma unroll
        for (int kk = 0; kk < 12; ++kk) {
            bf16x8 w0 = *(const bf16x8*)(cur + ml * 392 + kk * 32 + kg * 8);
            bf16x8 w1 = *(const bf16x8*)(cur + (16 + ml) * 392 + kk * 32 + kg * 8);
            a1acc[0][0] = __builtin_amdgcn_mfma_f32_16x16x32_bf16(w0, bfr[kk][0], a1acc[0][0], 0, 0, 0);
            a1acc[0][1] = __builtin_amdgcn_mfma_f32_16x16x32_bf16(w0, bfr[kk][1], a1acc[0][1], 0, 0, 0);
            a1acc[1][0] = __builtin_amdgcn_mfma_f32_16x16x32_bf16(w1, bfr[kk][0], a1acc[1][0], 0, 0, 0);
            a1acc[1][1] = __builtin_amdgcn_mfma_f32_16x16x32_bf16(w1, bfr[kk][1], a1acc[1][1], 0, 0, 0);
        }

        // bias + relu + bf16 pack -> wave-private transpose slot
        #pragma unroll
        for (int rt = 0; rt < 2; ++rt) {
            float4 b4 = *(const float4*)(fc1b + c * 32 + rt * 16 + kg * 4);
            #pragma unroll
            for (int st = 0; st < 2; ++st) {
                unsigned int p0 =
                    (unsigned int)bf16bits(fmaxf(a1acc[rt][st][0] + b4.x, 0.f))
                  | ((unsigned int)bf16bits(fmaxf(a1acc[rt][st][1] + b4.y, 0.f)) << 16);
                unsigned int p1 =
                    (unsigned int)bf16bits(fmaxf(a1acc[rt][st][2] + b4.z, 0.f))
                  | ((unsigned int)bf16bits(fmaxf(a1acc[rt][st][3] + b4.w, 0.f)) << 16);
                uint2 pk = {p0, p1};
                *(uint2*)(Tw + (st * 16 + ml) * 80 + (rt * 16 + kg * 4) * 2) = pk;
            }
        }
        asm volatile("s_waitcnt lgkmcnt(0)" ::: "memory");
        __builtin_amdgcn_sched_barrier(0);

        // fc2 partial: B-frags from transpose slot, A-frags (W2) from L2
        bf16x8 pf0 = *(const bf16x8*)(Tw + ml * 80 + kg * 16);
        bf16x8 pf1 = *(const bf16x8*)(Tw + (16 + ml) * 80 + kg * 16);
        #pragma unroll
        for (int t2 = 0; t2 < 4; ++t2) {
            bf16x8 a2 = *(const bf16x8*)(W2 + (t2 * 16 + ml) * 256 + c * 32 + kg * 8);
            acc2[t2][0] = __builtin_amdgcn_mfma_f32_16x16x32_bf16(a2, pf0, acc2[t2][0], 0, 0, 0);
            acc2[t2][1] = __builtin_amdgcn_mfma_f32_16x16x32_bf16(a2, pf1, acc2[t2][1], 0, 0, 0);
        }

        // stage next chunk into the other buffer (reads of it retired at the
        // barrier at top of THIS iteration; next reads occur after next barrier)
        if (c < 7) {
            __hip_bfloat16* nxt = (__hip_bfloat16*)(smem + ((c + 1) & 1) * 25088);
            #pragma unroll
            for (int it = 0; it < 6; ++it) {
                int v = tid + it * 256;
                int n = v / 48, k8 = v - n * 48;
                *(u16x8*)(nxt + n * 392 + k8 * 8) = nf[it];
            }
        }
    }

    // ---- head: h = relu(fc2+bias); logits = pw@h + pb; log_softmax ----
    #pragma unroll
    for (int st = 0; st < 2; ++st) {
        float h[16];
        #pragma unroll
        for (int t2 = 0; t2 < 4; ++t2) {
            float4 b4 = *(const float4*)(fc2b + t2 * 16 + kg * 4);
            #pragma unroll
            for (int i = 0; i < 4; ++i)
                h[t2 * 4 + i] = fmaxf(acc2[t2][st][i] + ((const float*)&b4)[i], 0.f);
        }
        float lg[12];
        #pragma unroll
        for (int j = 0; j < 12; ++j) {
            float s = 0.f;
            #pragma unroll
            for (int t2 = 0; t2 < 4; ++t2) {
                float4 wv = *(const float4*)(pwl + j * 64 + t2 * 16 + kg * 4);
                s += wv.x * h[t2 * 4 + 0] + wv.y * h[t2 * 4 + 1]
                   + wv.z * h[t2 * 4 + 2] + wv.w * h[t2 * 4 + 3];
            }
            lg[j] = s;
        }
        #pragma unroll
        for (int j = 0; j < 12; ++j) {
            lg[j] += __shfl_xor(lg[j], 16);
            lg[j] += __shfl_xor(lg[j], 32);
            lg[j] += pbl[j];
        }
        float m = lg[0];
        #pragma unroll
        for (int j = 1; j < 12; ++j) m = fmaxf(m, lg[j]);
        float e = 0.f;
        #pragma unroll
        for (int j = 0; j < 12; ++j) e += __expf(lg[j] - m);
        float lse = m + __logf(e);
        if (kg == 0) {
            float* op = out + (size_t)(blk * 128 + w * 32 + st * 16 + ml) * 12;
            float4 o0 = {lg[0] - lse, lg[1] - lse, lg[2]  - lse, lg[3]  - lse};
            float4 o1 = {lg[4] - lse, lg[5] - lse, lg[6]  - lse, lg[7]  - lse};
            float4 o2 = {lg[8] - lse, lg[9] - lse, lg[10] - lse, lg[11] - lse};
            ((float4*)op)[0] = o0; ((float4*)op)[1] = o1; ((float4*)op)[2] = o2;
        }
    }
}

extern "C" void kernel_launch(void* const* d_in, const int* in_sizes, int n_in,
                              void* d_out, int out_size, void* d_ws, size_t ws_size,
                              hipStream_t stream) {
    const float* sig = (const float*)d_in[0];
    const float* c1w = (const float*)d_in[1];
    const float* c1b = (const float*)d_in[2];
    const float* c2w = (const float*)d_in[3];
    const float* c2b = (const float*)d_in[4];
    const float* f1w = (const float*)d_in[5];
    const float* f1b = (const float*)d_in[6];
    const float* f2w = (const float*)d_in[7];
    const float* f2b = (const float*)d_in[8];
    const float* pw  = (const float*)d_in[9];
    const float* pb  = (const float*)d_in[10];
    float* out = (float*)d_out;

    __hip_bfloat16* W1 = (__hip_bfloat16*)d_ws;                    // [256][384] k'=o*36+t
    __hip_bfloat16* W2 = (__hip_bfloat16*)((char*)d_ws + 196608);  // [64][256]
    __hip_bfloat16* Fg = (__hip_bfloat16*)((char*)d_ws + 229376);  // [131072][384]

    prep_weights<<<448, 256, 0, stream>>>(f1w, f2w, W1, W2);
    features_kernel<<<16384, 256, 0, stream>>>(sig, c1w, c1b, c2w, c2b, Fg);
    fc_head_kernel<<<1024, 256, 0, stream>>>(Fg, W1, W2, f1b, f2b, pw, pb, out);
}

// Round 5
// 219.774 us; speedup vs baseline: 2.9516x; 1.1159x over previous
//
#include <hip/hip_runtime.h>
#include <hip/hip_bf16.h>

typedef __attribute__((ext_vector_type(8))) short bf16x8;
typedef __attribute__((ext_vector_type(4))) float f32x4;
typedef __attribute__((ext_vector_type(8))) unsigned short u16x8;

static __device__ __forceinline__ unsigned short bf16bits(float v) {
    __hip_bfloat16 h = __float2bfloat16(v);
    return *(unsigned short*)&h;
}

// ---- weight prep: fc1 K-permuted (k' = o*36+t) + zero-pad 360->384; fc2 ----
__global__ __launch_bounds__(256) void prep_weights(
    const float* __restrict__ fc1w, const float* __restrict__ fc2w,
    __hip_bfloat16* __restrict__ w1o, __hip_bfloat16* __restrict__ w2o)
{
    int id = blockIdx.x * 256 + threadIdx.x;
    if (id < 256 * 384) {
        int n = id / 384, k2 = id - n * 384;      // k2 = o*36 + t
        float v = 0.0f;
        if (k2 < 360) {
            int o = k2 / 36, t = k2 - o * 36;
            v = fc1w[n * 360 + t * 10 + o];
        }
        w1o[id] = __float2bfloat16(v);
    } else {
        int id2 = id - 256 * 384;
        if (id2 < 64 * 256) w2o[id2] = __float2bfloat16(fc2w[id2]);
    }
}

// =================== K1: features via MFMA convs ===========================
// 32 samples/block (2 tiles of 16), 256 thr, 4096 blocks, LDS 46920 B.
// Layouts (bf16, zero-initialized so K-pad lanes are exact 0):
//   P  @0     : 2 tiles x [16 smp][41 pos][8 ch] (stride 656B/smp) = 20992 B
//   SD @20992 : 2 tiles x [16 smp][43 pos][8 ch] (stride 688B/smp) = 22016 B
//   F  @20992 : [32 smp][392 k'] (over dead SD)                    = 25088 B
//   cw @46080 : 210 f32 conv consts
// conv as MFMA 16x16x32: A[s][k] = patch (k = kk*8+ch, 1 ds_read_b128),
// B[k][o] = weights in regs (built once). D: col=o (lane&15),
// row=sample (lane>>4)*4+i.
#define P_BASE  0
#define P_TILE  10496
#define P_SSTR  656
#define SD_BASE 20992
#define SD_TILE 11008
#define SD_SSTR 688
#define F_BASE  20992
#define F_RSTR  784
#define CW_OFF  46080
__global__ __launch_bounds__(256, 3) void features_kernel(
    const float* __restrict__ sig,
    const float* __restrict__ c1w_g, const float* __restrict__ c1b_g,
    const float* __restrict__ c2w_g, const float* __restrict__ c2b_g,
    __hip_bfloat16* __restrict__ Fg)
{
    __shared__ __align__(16) unsigned char smem[46920];
    float* cw = (float*)(smem + CW_OFF);

    const int tid  = threadIdx.x;
    const int blk  = blockIdx.x;
    const int wv   = tid >> 6;
    const int lane = tid & 63;
    const int ml   = lane & 15;
    const int kg   = lane >> 4;

    // phase -1: zero P+SD (MFMA K-pad safety) + stage conv consts
    {
        f32x4 z = {0.f, 0.f, 0.f, 0.f};
        for (int i = tid; i < 2688; i += 256)
            *(f32x4*)(smem + i * 16) = z;
        if (tid < 210) {
            float v;
            if (tid < 45)       v = c1w_g[tid];
            else if (tid < 50)  v = c1b_g[tid - 45];
            else if (tid < 200) v = c2w_g[tid - 50];
            else                v = c2b_g[tid - 200];
            cw[tid] = v;
        }
    }
    __syncthreads();

    // phase 0: running std (w=10, ddof=1), sliding. 192 threads: (s, c, half)
    if (tid < 192) {
        int s = tid / 6, r = tid - s * 6;
        int c = r >> 1, h = r & 1;
        int j0 = h * 20;
        const float* g = sig + (size_t)blk * 4800 + s * 150 + c;
        float x[30];
        #pragma unroll
        for (int j = 0; j < 30; ++j) x[j] = g[(j0 + j) * 3];
        float sum = 0.f, sq = 0.f;
        #pragma unroll
        for (int j = 0; j < 10; ++j) { sum += x[j]; sq += x[j] * x[j]; }
        unsigned char* sd = smem + SD_BASE + (s >> 4) * SD_TILE + (s & 15) * SD_SSTR + c * 2;
        #pragma unroll
        for (int i = 0; i < 20; ++i) {
            float var = (sq - sum * sum * 0.1f) * (1.0f / 9.0f);
            *(unsigned short*)(sd + (j0 + i) * 16) = bf16bits(sqrtf(fmaxf(var, 0.f)));
            if (i < 19) {
                float d = x[i + 10] - x[i];
                sq  += d * (x[i + 10] + x[i]);
                sum += d;
            }
        }
    }

    // conv weight B-fragments (regs, built once; K padded with exact zeros)
    // B1[k=kk*8+ci][o] = c1w[o][ci][kk]; B2[k=kk*8+i2][o] = c2w[o][i2][kk]
    bf16x8 B1f, B2f;
    #pragma unroll
    for (int j = 0; j < 8; ++j) {
        float v1 = (ml < 5  && kg < 3 && j < 3) ? cw[ml * 9 + j * 3 + kg] : 0.f;
        float v2 = (ml < 10 && kg < 3 && j < 5) ? cw[50 + ml * 15 + j * 3 + kg] : 0.f;
        B1f[j] = (short)bf16bits(v1);
        B2f[j] = (short)bf16bits(v2);
    }
    const float c1bias = (ml < 5)  ? cw[45 + ml]  : 0.f;
    const float c2bias = (ml < 10) ? cw[200 + ml] : 0.f;
    __syncthreads();

    // phase 1: conv1 (5,3,3)+relu via MFMA. wave -> (tile, t-half of 38)
    {
        const int tile = wv >> 1, half = wv & 1;
        const unsigned char* sdb = smem + SD_BASE + tile * SD_TILE + ml * SD_SSTR;
        unsigned char* pb = smem + P_BASE + tile * P_TILE + ml * 2;
        #pragma unroll
        for (int it = 0; it < 19; ++it) {
            int t = half * 19 + it;
            bf16x8 a = *(const bf16x8*)(sdb + (t + kg) * 16);
            f32x4 acc = {0.f, 0.f, 0.f, 0.f};
            acc = __builtin_amdgcn_mfma_f32_16x16x32_bf16(a, B1f, acc, 0, 0, 0);
            if (ml < 5) {
                #pragma unroll
                for (int i = 0; i < 4; ++i) {
                    float v = fmaxf(acc[i] + c1bias, 0.f);
                    *(unsigned short*)(pb + (kg * 4 + i) * P_SSTR + t * 16) = bf16bits(v);
                }
            }
        }
    }
    __syncthreads();

    // zero F k'-tail cols [360,392) (over dead SD region)
    if (tid < 128) {
        f32x4 z = {0.f, 0.f, 0.f, 0.f};
        int r = tid >> 2, q = tid & 3;
        *(f32x4*)(smem + F_BASE + r * F_RSTR + 720 + q * 16) = z;
    }

    // phase 2: conv2 (10,5,3)+relu via MFMA -> F[s][o*36+t]
    {
        const int tile = wv >> 1, half = wv & 1;
        const unsigned char* pbr = smem + P_BASE + tile * P_TILE + ml * P_SSTR;
        unsigned char* fb = smem + F_BASE + tile * 16 * F_RSTR + ml * 72;
        #pragma unroll
        for (int it = 0; it < 18; ++it) {
            int t = half * 18 + it;
            bf16x8 a = *(const bf16x8*)(pbr + (t + kg) * 16);
            f32x4 acc = {0.f, 0.f, 0.f, 0.f};
            acc = __builtin_amdgcn_mfma_f32_16x16x32_bf16(a, B2f, acc, 0, 0, 0);
            if (ml < 10) {
                #pragma unroll
                for (int i = 0; i < 4; ++i) {
                    float v = fmaxf(acc[i] + c2bias, 0.f);
                    *(unsigned short*)(fb + (kg * 4 + i) * F_RSTR + t * 2) = bf16bits(v);
                }
            }
        }
    }
    __syncthreads();

    // phase 3: coalesced copy-out F[32][384] -> Fg
    {
        u16x8* dstv = (u16x8*)Fg + (size_t)blk * 1536;
        for (int i = tid; i < 1536; i += 256) {
            int r = i / 48, cc = i - r * 48;
            dstv[i] = *(const u16x8*)(smem + F_BASE + r * F_RSTR + cc * 16);
        }
    }
}

// =================== K2: fc1 + fc2 + pamap head + log_softmax ==============
// 128 samples/block, 1024 blocks, 4 waves; wave = 32 samples x all 256 rows.
// W1 double-buffered in LDS (one barrier/chunk); W2 fragments register-
// prefetched one chunk ahead (removes in-loop L2 latency).
__global__ __launch_bounds__(256, 2) void fc_head_kernel(
    const __hip_bfloat16* __restrict__ Fg,
    const __hip_bfloat16* __restrict__ W1, const __hip_bfloat16* __restrict__ W2,
    const float* __restrict__ fc1b, const float* __restrict__ fc2b,
    const float* __restrict__ pw, const float* __restrict__ pb,
    float* __restrict__ out)
{
    __shared__ __align__(16) unsigned char smem[63536];
    float* pwl = (float*)(smem + 60416);
    float* pbl = (float*)(smem + 63488);

    const int tid  = threadIdx.x;
    const int blk  = blockIdx.x;
    const int w    = tid >> 6;
    const int lane = tid & 63;
    const int ml   = lane & 15;
    const int kg   = lane >> 4;
    unsigned char* Tw = smem + 50176 + w * 2560;   // [32 samples][80B]

    for (int i = tid; i < 780; i += 256) {
        if (i < 768) pwl[i] = pw[i]; else pbl[i - 768] = pb[i - 768];
    }

    // activation B-fragments (whole kernel in regs)
    const __hip_bfloat16* myF = Fg + (size_t)(blk * 128 + w * 32 + ml) * 384;
    bf16x8 bfr[12][2];
    #pragma unroll
    for (int kk = 0; kk < 12; ++kk) {
        bfr[kk][0] = *(const bf16x8*)(myF + kk * 32 + kg * 8);
        bfr[kk][1] = *(const bf16x8*)(myF + 16 * 384 + kk * 32 + kg * 8);
    }

    // stage W1 chunk 0 into buffer 0; prefetch W2 chunk-0 frags into regs
    {
        const u16x8* src = (const u16x8*)W1;
        __hip_bfloat16* b0 = (__hip_bfloat16*)smem;
        #pragma unroll
        for (int it = 0; it < 6; ++it) {
            int v = tid + it * 256;
            int n = v / 48, k8 = v - n * 48;
            *(u16x8*)(b0 + n * 392 + k8 * 8) = src[v];
        }
    }
    bf16x8 a2f[4];
    #pragma unroll
    for (int t2 = 0; t2 < 4; ++t2)
        a2f[t2] = *(const bf16x8*)(W2 + (t2 * 16 + ml) * 256 + kg * 8);

    f32x4 acc2[4][2];
    #pragma unroll
    for (int t2 = 0; t2 < 4; ++t2) {
        acc2[t2][0] = f32x4{0, 0, 0, 0};
        acc2[t2][1] = f32x4{0, 0, 0, 0};
    }

    for (int c = 0; c < 8; ++c) {
        __syncthreads();   // buf[c&1] staged & prior reads retired
        const __hip_bfloat16* cur = (const __hip_bfloat16*)(smem + (c & 1) * 25088);

        // prefetch next chunk: W1 rows to regs, W2 frags to regs
        u16x8 nf[6];
        bf16x8 a2n[4];
        if (c < 7) {
            const u16x8* src = (const u16x8*)(W1 + (c + 1) * 32 * 384);
            #pragma unroll
            for (int it = 0; it < 6; ++it) nf[it] = src[tid + it * 256];
            #pragma unroll
            for (int t2 = 0; t2 < 4; ++t2)
                a2n[t2] = *(const bf16x8*)(W2 + (t2 * 16 + ml) * 256 + (c + 1) * 32 + kg * 8);
        }

        // fc1: 2 row-tiles x 2 sample-tiles
        f32x4 a1acc[2][2];
        #pragma unroll
        for (int rt = 0; rt < 2; ++rt) {
            a1acc[rt][0] = f32x4{0, 0, 0, 0};
            a1acc[rt][1] = f32x4{0, 0, 0, 0};
        }
        #pragma unroll
        for (int kk = 0; kk < 12; ++kk) {
            bf16x8 w0 = *(const bf16x8*)(cur + ml * 392 + kk * 32 + kg * 8);
            bf16x8 w1 = *(const bf16x8*)(cur + (16 + ml) * 392 + kk * 32 + kg * 8);
            a1acc[0][0] = __builtin_amdgcn_mfma_f32_16x16x32_bf16(w0, bfr[kk][0], a1acc[0][0], 0, 0, 0);
            a1acc[0][1] = __builtin_amdgcn_mfma_f32_16x16x32_bf16(w0, bfr[kk][1], a1acc[0][1], 0, 0, 0);
            a1acc[1][0] = __builtin_amdgcn_mfma_f32_16x16x32_bf16(w1, bfr[kk][0], a1acc[1][0], 0, 0, 0);
            a1acc[1][1] = __builtin_amdgcn_mfma_f32_16x16x32_bf16(w1, bfr[kk][1], a1acc[1][1], 0, 0, 0);
        }

        // bias + relu + bf16 pack -> wave-private transpose slot
        #pragma unroll
        for (int rt = 0; rt < 2; ++rt) {
            float4 b4 = *(const float4*)(fc1b + c * 32 + rt * 16 + kg * 4);
            #pragma unroll
            for (int st = 0; st < 2; ++st) {
                unsigned int p0 =
                    (unsigned int)bf16bits(fmaxf(a1acc[rt][st][0] + b4.x, 0.f))
                  | ((unsigned int)bf16bits(fmaxf(a1acc[rt][st][1] + b4.y, 0.f)) << 16);
                unsigned int p1 =
                    (unsigned int)bf16bits(fmaxf(a1acc[rt][st][2] + b4.z, 0.f))
                  | ((unsigned int)bf16bits(fmaxf(a1acc[rt][st][3] + b4.w, 0.f)) << 16);
                uint2 pk = {p0, p1};
                *(uint2*)(Tw + (st * 16 + ml) * 80 + (rt * 16 + kg * 4) * 2) = pk;
            }
        }
        asm volatile("s_waitcnt lgkmcnt(0)" ::: "memory");
        __builtin_amdgcn_sched_barrier(0);

        // fc2 partial: B-frags from transpose slot, A-frags prefetched regs
        bf16x8 pf0 = *(const bf16x8*)(Tw + ml * 80 + kg * 16);
        bf16x8 pf1 = *(const bf16x8*)(Tw + (16 + ml) * 80 + kg * 16);
        #pragma unroll
        for (int t2 = 0; t2 < 4; ++t2) {
            acc2[t2][0] = __builtin_amdgcn_mfma_f32_16x16x32_bf16(a2f[t2], pf0, acc2[t2][0], 0, 0, 0);
            acc2[t2][1] = __builtin_amdgcn_mfma_f32_16x16x32_bf16(a2f[t2], pf1, acc2[t2][1], 0, 0, 0);
        }

        // stage next W1 chunk; roll W2 frags
        if (c < 7) {
            __hip_bfloat16* nxt = (__hip_bfloat16*)(smem + ((c + 1) & 1) * 25088);
            #pragma unroll
            for (int it = 0; it < 6; ++it) {
                int v = tid + it * 256;
                int n = v / 48, k8 = v - n * 48;
                *(u16x8*)(nxt + n * 392 + k8 * 8) = nf[it];
            }
            #pragma unroll
            for (int t2 = 0; t2 < 4; ++t2) a2f[t2] = a2n[t2];
        }
    }

    // ---- head: h = relu(fc2+bias); logits = pw@h + pb; log_softmax ----
    #pragma unroll
    for (int st = 0; st < 2; ++st) {
        float h[16];
        #pragma unroll
        for (int t2 = 0; t2 < 4; ++t2) {
            float4 b4 = *(const float4*)(fc2b + t2 * 16 + kg * 4);
            #pragma unroll
            for (int i = 0; i < 4; ++i)
                h[t2 * 4 + i] = fmaxf(acc2[t2][st][i] + ((const float*)&b4)[i], 0.f);
        }
        float lg[12];
        #pragma unroll
        for (int j = 0; j < 12; ++j) {
            float s = 0.f;
            #pragma unroll
            for (int t2 = 0; t2 < 4; ++t2) {
                float4 wv4 = *(const float4*)(pwl + j * 64 + t2 * 16 + kg * 4);
                s += wv4.x * h[t2 * 4 + 0] + wv4.y * h[t2 * 4 + 1]
                   + wv4.z * h[t2 * 4 + 2] + wv4.w * h[t2 * 4 + 3];
            }
            lg[j] = s;
        }
        #pragma unroll
        for (int j = 0; j < 12; ++j) {
            lg[j] += __shfl_xor(lg[j], 16);
            lg[j] += __shfl_xor(lg[j], 32);
            lg[j] += pbl[j];
        }
        float m = lg[0];
        #pragma unroll
        for (int j = 1; j < 12; ++j) m = fmaxf(m, lg[j]);
        float e = 0.f;
        #pragma unroll
        for (int j = 0; j < 12; ++j) e += __expf(lg[j] - m);
        float lse = m + __logf(e);
        if (kg == 0) {
            float* op = out + (size_t)(blk * 128 + w * 32 + st * 16 + ml) * 12;
            float4 o0 = {lg[0] - lse, lg[1] - lse, lg[2]  - lse, lg[3]  - lse};
            float4 o1 = {lg[4] - lse, lg[5] - lse, lg[6]  - lse, lg[7]  - lse};
            float4 o2 = {lg[8] - lse, lg[9] - lse, lg[10] - lse, lg[11] - lse};
            ((float4*)op)[0] = o0; ((float4*)op)[1] = o1; ((float4*)op)[2] = o2;
        }
    }
}

extern "C" void kernel_launch(void* const* d_in, const int* in_sizes, int n_in,
                              void* d_out, int out_size, void* d_ws, size_t ws_size,
                              hipStream_t stream) {
    const float* sig = (const float*)d_in[0];
    const float* c1w = (const float*)d_in[1];
    const float* c1b = (const float*)d_in[2];
    const float* c2w = (const float*)d_in[3];
    const float* c2b = (const float*)d_in[4];
    const float* f1w = (const float*)d_in[5];
    const float* f1b = (const float*)d_in[6];
    const float* f2w = (const float*)d_in[7];
    const float* f2b = (const float*)d_in[8];
    const float* pw  = (const float*)d_in[9];
    const float* pb  = (const float*)d_in[10];
    float* out = (float*)d_out;

    __hip_bfloat16* W1 = (__hip_bfloat16*)d_ws;                    // [256][384] k'=o*36+t
    __hip_bfloat16* W2 = (__hip_bfloat16*)((char*)d_ws + 196608);  // [64][256]
    __hip_bfloat16* Fg = (__hip_bfloat16*)((char*)d_ws + 229376);  // [131072][384]

    prep_weights<<<448, 256, 0, stream>>>(f1w, f2w, W1, W2);
    features_kernel<<<4096, 256, 0, stream>>>(sig, c1w, c1b, c2w, c2b, Fg);
    fc_head_kernel<<<1024, 256, 0, stream>>>(Fg, W1, W2, f1b, f2b, pw, pb, out);
}